// Round 7
// baseline (315.779 us; speedup 1.0000x reference)
//
#include <hip/hip_runtime.h>
#include <math.h>

namespace {
constexpr int K = 16, T = 8, R = 8, NB = 32;
constexpr int NX = 64, NY = 64, NZ = 32;
constexpr int NVOX = NX * NY * NZ;                 // 131072
constexpr float TWO_PI_OVER_C = (float)(6.283185307179586 / 299792458.0);
constexpr float CT_SCALE = 4.0f / 256.0f;          // scale split across Ht,Hr; cancels in normalize
constexpr float CR_SCALE = 1.0f / 256.0f;
// B table: [tr(64)][out(2)][quad(4)][n(32)][j(8)] halves = 262144 B
constexpr int B_HALVES = 64 * 2 * 4 * 32 * 8;      // 131072
constexpr size_t WS_NEED = 256 + (size_t)B_HALVES * 2;
}

typedef _Float16 half8 __attribute__((ext_vector_type(8)));
typedef __fp16 fp16x2 __attribute__((ext_vector_type(2)));   // cvt_pkrtz native type
typedef float f32x4 __attribute__((ext_vector_type(4)));

// ---------------------------------------------------------------------------
// Prep: zero max slot; build B fragments in ws.
// B[k'][n] per (tr, out):  k'<16 -> (out0: yre, out1: yim),  k'>=16 -> (out0: -yim, out1: yre)
// ---------------------------------------------------------------------------
__global__ void prep_kernel(const float* __restrict__ yr, const float* __restrict__ yi,
                            _Float16* __restrict__ wsB, unsigned int* __restrict__ maxslot,
                            int use_ws) {
    int id = blockIdx.x * 256 + threadIdx.x;   // 16384 threads
    if (id == 0) *maxslot = 0u;
    if (!use_ws || id >= 64 * 2 * 4 * 32) return;
    int n    = id & 31;
    int quad = (id >> 5) & 3;
    int outc = (id >> 7) & 1;
    int tr   = id >> 8;
    int t = tr >> 3, r = tr & 7;
    bool second = quad >= 2;                    // k' >= 16 half (pairs with AIm)
    const float* src = (outc == 0) ? (second ? yi : yr) : (second ? yr : yi);
    float sg = (outc == 0 && second) ? -1.0f : 1.0f;
    int base = n * (K * T * R) + ((quad & 1) * 8) * (T * R) + t * R + r;
    half8 h;
#pragma unroll
    for (int j = 0; j < 8; ++j)
        h[j] = (_Float16)(sg * src[base + j * (T * R)]);
    ((half8*)wsB)[id] = h;
}

// ---------------------------------------------------------------------------
// Main: per wave, 16-voxel x 32-batch complex tile via MFMA.
// A = 4*Ht*Hr: Hr in LDS (built once per block), X/Z fragments prefetched
// one iteration ahead into a 2-deep register ping-pong. Ht per t in fp32
// registers with quad-class sign folded into him. A computed in fp32 via
// v_fma_mix, single fp16 rounding. B loads: depth-2 register pipeline.
// ---------------------------------------------------------------------------
template <bool USE_WS>
__global__ __launch_bounds__(256, 3) void kirch_mfma(
    const float* __restrict__ freqs,
    const float* __restrict__ txp, const float* __restrict__ rxp,
    const float* __restrict__ xc, const float* __restrict__ yc, const float* __restrict__ zc,
    const _Float16* __restrict__ wsB,
    const float* __restrict__ yr, const float* __restrict__ yi,
    float* __restrict__ out, unsigned int* __restrict__ maxslot)
{
    __shared__ _Float16 sHrRe[8][2][64][8];   // [r][kh][vox][j]  16 KB
    __shared__ _Float16 sHrIm[8][2][64][8];   // 16 KB
    __shared__ float s_wmax[4];

    const int tid  = threadIdx.x;
    const int lane = tid & 63;
    const int wave = tid >> 6;
    const int nlo  = lane & 15;
    const int quad = lane >> 4;
    const int kh   = quad & 1;
    const int vb   = blockIdx.x * 64 + wave * 16;
    const int v    = vb + nlo;                 // this lane's voxel (fragment row m)
    const int bv2  = wave * 16 + nlo;          // block-local voxel index

    const float k0 = TWO_PI_OVER_C * freqs[0];
    const float dk = TWO_PI_OVER_C * (freqs[K - 1] - freqs[0]) * (1.0f / (K - 1));

    // ---- Phase 1: cooperatively build Hr table (64 vox x 8 r x 16 k) ----
#pragma unroll
    for (int s = 0; s < 2; ++s) {
        int task = tid + (s << 8);             // 512 tasks
        int bv = task & 63;
        int r  = task >> 6;
        int gv = blockIdx.x * 64 + bv;
        float qx = xc[gv >> 11];
        float qy = yc[(gv >> 5) & 63];
        float qz = zc[gv & 31];
        float rxx = rxp[r * 3 + 0], rxy = rxp[r * 3 + 1], rxz = rxp[r * 3 + 2];
        float dx = qx - rxx, dy = qy - rxy, dz = qz - rxz;
        float Rr = sqrtf(dx * dx + dy * dy + dz * dz);
        float c = CR_SCALE * dz * __builtin_amdgcn_rcpf(Rr);
        float sph, cph, swp, cwp;
        __sincosf(k0 * Rr, &sph, &cph);
        __sincosf(dk * Rr, &swp, &cwp);
        float ur = cph, ui = sph;
        float ck = c * (k0 * Rr);
        const float dck = c * (dk * Rr);
        float re[16], im[16];
#pragma unroll
        for (int kk = 0; kk < 16; ++kk) {
            re[kk] = fmaf(c, ur, -(ck * ui));   // c*(ur - kR*ui)
            im[kk] = fmaf(c, ui,  (ck * ur));   // c*(ui + kR*ur)
            float nr = fmaf(ur, cwp, -(ui * swp));
            ui = fmaf(ur, swp, ui * cwp);
            ur = nr;
            ck += dck;
        }
        union { half8 v8; fp16x2 v2[4]; } h;
#pragma unroll
        for (int kk2 = 0; kk2 < 2; ++kk2) {
#pragma unroll
            for (int i = 0; i < 4; ++i)
                h.v2[i] = __builtin_amdgcn_cvt_pkrtz(re[kk2 * 8 + 2 * i], re[kk2 * 8 + 2 * i + 1]);
            *(half8*)&sHrRe[r][kk2][bv][0] = h.v8;
#pragma unroll
            for (int i = 0; i < 4; ++i)
                h.v2[i] = __builtin_amdgcn_cvt_pkrtz(im[kk2 * 8 + 2 * i], im[kk2 * 8 + 2 * i + 1]);
            *(half8*)&sHrIm[r][kk2][bv][0] = h.v8;
        }
    }
    __syncthreads();

    // ---- X/Z plane base pointers (per lane class) ----
    // Re-quads: A = HtRe*HrRe - HtIm*HrIm  -> X=HrRe, Z=HrIm, him sign = -
    // Im-quads: A = HtRe*HrIm + HtIm*HrRe  -> X=HrIm, Z=HrRe, him sign = +
    const _Float16* pX = (quad < 2) ? &sHrRe[0][kh][bv2][0] : &sHrIm[0][kh][bv2][0];
    const _Float16* pZ = (quad < 2) ? &sHrIm[0][kh][bv2][0] : &sHrRe[0][kh][bv2][0];
    const float simsgn = (quad < 2) ? -1.0f : 1.0f;

    // ---- per-lane constants ----
    const float px = xc[v >> 11];
    const float py = yc[(v >> 5) & 63];
    const float pz = zc[v & 31];
    const float kstart = k0 + (kh ? 8.0f * dk : 0.0f);

    f32x4 accRe0 = {0,0,0,0}, accRe1 = {0,0,0,0};
    f32x4 accIm0 = {0,0,0,0}, accIm1 = {0,0,0,0};

    // ---- B load pipeline: depth-2 register ping-pong, uniform stride ----
    half8 pb[2][4];
    const char* bptr = (const char*)wsB + quad * 512 + nlo * 16;  // +=4096 per tr
    int tr_issue = 0;
    auto issueB = [&](int slot) {
        if (USE_WS) {
            pb[slot][0] = *(const half8*)(bptr);             // Re-out, ntile 0
            pb[slot][1] = *(const half8*)(bptr + 256);       // Re-out, ntile 1
            pb[slot][2] = *(const half8*)(bptr + 2048);      // Im-out, ntile 0
            pb[slot][3] = *(const half8*)(bptr + 2304);      // Im-out, ntile 1
            bptr += 4096;
        } else {
            const int tr = tr_issue;
            const int kb = kh * 8;
            const float* sA = (quad < 2) ? yr : yi;
            const float sgA = (quad < 2) ? 1.0f : -1.0f;
            const float* sB = (quad < 2) ? yi : yr;
            auto gather = [&](const float* src, float sg, int n) {
                int base = n * (K * T * R) + kb * (T * R) + tr;
                half8 h;
#pragma unroll
                for (int j = 0; j < 8; ++j) h[j] = (_Float16)(sg * src[base + j * (T * R)]);
                return h;
            };
            pb[slot][0] = gather(sA, sgA, nlo);
            pb[slot][1] = gather(sA, sgA, 16 + nlo);
            pb[slot][2] = gather(sB, 1.0f, nlo);
            pb[slot][3] = gather(sB, 1.0f, 16 + nlo);
        }
        ++tr_issue;
    };
    issueB(0);   // tr 0
    issueB(1);   // tr 1

    // ---- Hr fragment prefetch ping-pong (LDS -> regs, 1 iter ahead) ----
    half8 Xb[2], Zb[2];
    Xb[0] = *(const half8*)(pX);
    Zb[0] = *(const half8*)(pZ);

    for (int t = 0; t < T; ++t) {
        // ---- Ht for this (voxel, t) over the lane's 8 freqs, fp32, sign folded ----
        const float txx = txp[t * 3 + 0], txy = txp[t * 3 + 1], txz = txp[t * 3 + 2];
        const float dxt = px - txx, dyt = py - txy, dzt = pz - txz;
        const float Rt = sqrtf(dxt * dxt + dyt * dyt + dzt * dzt);
        const float c = CT_SCALE * dzt * __builtin_amdgcn_rcpf(Rt);
        const float cIm = simsgn * c;
        float sph, cph, swp, cwp;
        __sincosf(kstart * Rt, &sph, &cph);
        __sincosf(dk * Rt, &swp, &cwp);
        float ur = cph, ui = sph;
        float ck  = c * (kstart * Rt);
        float ckI = cIm * (kstart * Rt);
        const float dck  = c * (dk * Rt);
        const float dckI = cIm * (dk * Rt);
        float hre[8], him[8];
#pragma unroll
        for (int j = 0; j < 8; ++j) {
            hre[j] = fmaf(c,   ur, -(ck * ui));    //  c*(ur - kR*ui)
            him[j] = fmaf(cIm, ui,  (ckI * ur));   // ±c*(ui + kR*ur)
            if (j < 7) {
                float nr = fmaf(ur, cwp, -(ui * swp));
                ui = fmaf(ur, swp, ui * cwp);
                ur = nr;
                ck  += dck;
                ckI += dckI;
            }
        }

#pragma unroll
        for (int r = 0; r < R; ++r) {
            const int tr = t * 8 + r;
            const int cur = tr & 1;
            const int nxt = cur ^ 1;

            // prefetch next iteration's Hr fragments (wave-uniform branch)
            if (tr < 63) {
                const int rn = (tr + 1) & 7;
                Xb[nxt] = *(const half8*)(pX + rn * 1024);
                Zb[nxt] = *(const half8*)(pZ + rn * 1024);
            }

            // A fragment: fp32 mixed-precision product (v_fma_mix), one fp16 rounding
            half8 X = Xb[cur], Z = Zb[cur];
            union { half8 v8; fp16x2 v2[4]; } A;
#pragma unroll
            for (int i = 0; i < 4; ++i) {
                float v0 = fmaf(hre[2 * i],     (float)X[2 * i],     him[2 * i]     * (float)Z[2 * i]);
                float v1 = fmaf(hre[2 * i + 1], (float)X[2 * i + 1], him[2 * i + 1] * (float)Z[2 * i + 1]);
                A.v2[i] = __builtin_amdgcn_cvt_pkrtz(v0, v1);
            }

            half8 b0 = pb[cur][0], b1 = pb[cur][1], b2 = pb[cur][2], b3 = pb[cur][3];
            if (tr < 62) issueB(cur);          // keep 2 tr of B in flight
            accRe0 = __builtin_amdgcn_mfma_f32_16x16x32_f16(A.v8, b0, accRe0, 0, 0, 0);
            accRe1 = __builtin_amdgcn_mfma_f32_16x16x32_f16(A.v8, b1, accRe1, 0, 0, 0);
            accIm0 = __builtin_amdgcn_mfma_f32_16x16x32_f16(A.v8, b2, accIm0, 0, 0, 0);
            accIm1 = __builtin_amdgcn_mfma_f32_16x16x32_f16(A.v8, b3, accIm1, 0, 0, 0);
        }
    }

    // ---- epilogue: magnitudes, store, block max ----
    // C/D layout: n = ntile*16 + (lane&15), m(voxel) = quad*4 + reg
    float mx = 0.0f;
#pragma unroll
    for (int reg = 0; reg < 4; ++reg) {
        const int vv = vb + quad * 4 + reg;
        float re0 = accRe0[reg], im0 = accIm0[reg];
        float m0 = sqrtf(re0 * re0 + im0 * im0);
        out[nlo * NVOX + vv] = m0;
        float re1 = accRe1[reg], im1 = accIm1[reg];
        float m1 = sqrtf(re1 * re1 + im1 * im1);
        out[(16 + nlo) * NVOX + vv] = m1;
        mx = fmaxf(mx, fmaxf(m0, m1));
    }
#pragma unroll
    for (int off = 32; off > 0; off >>= 1)
        mx = fmaxf(mx, __shfl_down(mx, off));
    if (lane == 0) s_wmax[wave] = mx;
    __syncthreads();
    if (threadIdx.x == 0) {
        float bm = fmaxf(fmaxf(s_wmax[0], s_wmax[1]), fmaxf(s_wmax[2], s_wmax[3]));
        atomicMax(maxslot, __float_as_uint(bm));
    }
}

// ---------------------------------------------------------------------------
// Normalize: out *= 1/max
// ---------------------------------------------------------------------------
__global__ void normalize_kernel(float* __restrict__ out,
                                 const unsigned int* __restrict__ maxslot, int n4) {
    int i = blockIdx.x * blockDim.x + threadIdx.x;
    float inv = 1.0f / __uint_as_float(*maxslot);
    if (i < n4) {
        float4* o = (float4*)out;
        float4 vv = o[i];
        vv.x *= inv; vv.y *= inv; vv.z *= inv; vv.w *= inv;
        o[i] = vv;
    }
}

extern "C" void kernel_launch(void* const* d_in, const int* in_sizes, int n_in,
                              void* d_out, int out_size, void* d_ws, size_t ws_size,
                              hipStream_t stream) {
    const float* freqs = (const float*)d_in[0];
    const float* txp   = (const float*)d_in[1];
    const float* rxp   = (const float*)d_in[2];
    const float* xc    = (const float*)d_in[3];
    const float* yc    = (const float*)d_in[4];
    const float* zc    = (const float*)d_in[5];
    const float* yr    = (const float*)d_in[6];
    const float* yi    = (const float*)d_in[7];
    float* out = (float*)d_out;

    unsigned int* maxslot = (unsigned int*)d_ws;
    _Float16* wsB = (_Float16*)((char*)d_ws + 256);
    const int use_ws = (ws_size >= WS_NEED) ? 1 : 0;

    prep_kernel<<<64, 256, 0, stream>>>(yr, yi, wsB, maxslot, use_ws);

    if (use_ws)
        kirch_mfma<true><<<NVOX / 64, 256, 0, stream>>>(
            freqs, txp, rxp, xc, yc, zc, wsB, yr, yi, out, maxslot);
    else
        kirch_mfma<false><<<NVOX / 64, 256, 0, stream>>>(
            freqs, txp, rxp, xc, yc, zc, wsB, yr, yi, out, maxslot);

    int n4 = out_size / 4;
    normalize_kernel<<<(n4 + 255) / 256, 256, 0, stream>>>(out, maxslot, n4);
}

// Round 8
// 303.691 us; speedup vs baseline: 1.0398x; 1.0398x over previous
//
#include <hip/hip_runtime.h>
#include <math.h>

namespace {
constexpr int K = 16, T = 8, R = 8, NB = 32;
constexpr int NX = 64, NY = 64, NZ = 32;
constexpr int NVOX = NX * NY * NZ;                 // 131072
constexpr float TWO_PI_OVER_C = (float)(6.283185307179586 / 299792458.0);
constexpr float CT_SCALE = 4.0f / 256.0f;          // scale split across Ht,Hr; cancels in normalize
constexpr float CR_SCALE = 1.0f / 256.0f;
// B table: [tr(64)][out(2)][quad(4)][n(32)][j(8)] halves = 262144 B
constexpr int B_HALVES = 64 * 2 * 4 * 32 * 8;      // 131072
constexpr size_t WS_NEED = 256 + (size_t)B_HALVES * 2;
}

typedef _Float16 half8 __attribute__((ext_vector_type(8)));
typedef __fp16 fp16x2 __attribute__((ext_vector_type(2)));   // cvt_pkrtz native type
typedef float f32x4 __attribute__((ext_vector_type(4)));

// ---------------------------------------------------------------------------
// Prep: zero max slot; build B fragments in ws.
// B[k'][n] per (tr, out):  k'<16 -> (out0: yre, out1: yim),  k'>=16 -> (out0: -yim, out1: yre)
// ---------------------------------------------------------------------------
__global__ void prep_kernel(const float* __restrict__ yr, const float* __restrict__ yi,
                            _Float16* __restrict__ wsB, unsigned int* __restrict__ maxslot,
                            int use_ws) {
    int id = blockIdx.x * 256 + threadIdx.x;   // 16384 threads
    if (id == 0) *maxslot = 0u;
    if (!use_ws || id >= 64 * 2 * 4 * 32) return;
    int n    = id & 31;
    int quad = (id >> 5) & 3;
    int outc = (id >> 7) & 1;
    int tr   = id >> 8;
    int t = tr >> 3, r = tr & 7;
    bool second = quad >= 2;                    // k' >= 16 half (pairs with AIm)
    const float* src = (outc == 0) ? (second ? yi : yr) : (second ? yr : yi);
    float sg = (outc == 0 && second) ? -1.0f : 1.0f;
    int base = n * (K * T * R) + ((quad & 1) * 8) * (T * R) + t * R + r;
    half8 h;
#pragma unroll
    for (int j = 0; j < 8; ++j)
        h[j] = (_Float16)(sg * src[base + j * (T * R)]);
    ((half8*)wsB)[id] = h;
}

// ---------------------------------------------------------------------------
// Main: per wave, 16-voxel x 32-batch complex tile via MFMA.
// A = 4*Ht*Hr. Hr in LDS (one cooperative build per block). Ht per t in fp32
// regs, quad-class sign folded into him. A computed fp32 (v_fma_mix), one
// fp16 rounding. B + Hr fragments prefetched one iteration ahead into
// ping-pong arrays indexed ONLY by unroll-constant r&1 (SROA-safe; no
// lambdas, no mutable pointer chains -> no scratch).
// ---------------------------------------------------------------------------
template <bool USE_WS>
__global__ __launch_bounds__(256, 3) void kirch_mfma(
    const float* __restrict__ freqs,
    const float* __restrict__ txp, const float* __restrict__ rxp,
    const float* __restrict__ xc, const float* __restrict__ yc, const float* __restrict__ zc,
    const _Float16* __restrict__ wsB,
    const float* __restrict__ yr, const float* __restrict__ yi,
    float* __restrict__ out, unsigned int* __restrict__ maxslot)
{
    __shared__ _Float16 sHrRe[8][2][64][8];   // [r][kh][vox][j]  16 KB
    __shared__ _Float16 sHrIm[8][2][64][8];   // 16 KB
    __shared__ float s_wmax[4];

    const int tid  = threadIdx.x;
    const int lane = tid & 63;
    const int wave = tid >> 6;
    const int nlo  = lane & 15;
    const int quad = lane >> 4;
    const int kh   = quad & 1;
    const int vb   = blockIdx.x * 64 + wave * 16;
    const int v    = vb + nlo;                 // this lane's voxel (fragment row m)
    const int bv2  = wave * 16 + nlo;          // block-local voxel index

    const float k0 = TWO_PI_OVER_C * freqs[0];
    const float dk = TWO_PI_OVER_C * (freqs[K - 1] - freqs[0]) * (1.0f / (K - 1));

    // ---- Phase 1: cooperatively build Hr table (64 vox x 8 r x 16 k) ----
#pragma unroll
    for (int s = 0; s < 2; ++s) {
        int task = tid + (s << 8);             // 512 tasks
        int bv = task & 63;
        int r  = task >> 6;
        int gv = blockIdx.x * 64 + bv;
        float qx = xc[gv >> 11];
        float qy = yc[(gv >> 5) & 63];
        float qz = zc[gv & 31];
        float rxx = rxp[r * 3 + 0], rxy = rxp[r * 3 + 1], rxz = rxp[r * 3 + 2];
        float dx = qx - rxx, dy = qy - rxy, dz = qz - rxz;
        float Rr = sqrtf(dx * dx + dy * dy + dz * dz);
        float c = CR_SCALE * dz * __builtin_amdgcn_rcpf(Rr);
        float sph, cph, swp, cwp;
        __sincosf(k0 * Rr, &sph, &cph);
        __sincosf(dk * Rr, &swp, &cwp);
        float ur = cph, ui = sph;
        float ck = c * (k0 * Rr);
        const float dck = c * (dk * Rr);
        float re[16], im[16];
#pragma unroll
        for (int kk = 0; kk < 16; ++kk) {
            re[kk] = fmaf(c, ur, -(ck * ui));   // c*(ur - kR*ui)
            im[kk] = fmaf(c, ui,  (ck * ur));   // c*(ui + kR*ur)
            float nr = fmaf(ur, cwp, -(ui * swp));
            ui = fmaf(ur, swp, ui * cwp);
            ur = nr;
            ck += dck;
        }
        union { half8 v8; fp16x2 v2[4]; } h;
#pragma unroll
        for (int kk2 = 0; kk2 < 2; ++kk2) {
#pragma unroll
            for (int i = 0; i < 4; ++i)
                h.v2[i] = __builtin_amdgcn_cvt_pkrtz(re[kk2 * 8 + 2 * i], re[kk2 * 8 + 2 * i + 1]);
            *(half8*)&sHrRe[r][kk2][bv][0] = h.v8;
#pragma unroll
            for (int i = 0; i < 4; ++i)
                h.v2[i] = __builtin_amdgcn_cvt_pkrtz(im[kk2 * 8 + 2 * i], im[kk2 * 8 + 2 * i + 1]);
            *(half8*)&sHrIm[r][kk2][bv][0] = h.v8;
        }
    }
    __syncthreads();

    // ---- X/Z plane base pointers (per lane class) ----
    // Re-quads: A = HtRe*HrRe - HtIm*HrIm  -> X=HrRe, Z=HrIm, him sign = -
    // Im-quads: A = HtRe*HrIm + HtIm*HrRe  -> X=HrIm, Z=HrRe, him sign = +
    const _Float16* pX = (quad < 2) ? &sHrRe[0][kh][bv2][0] : &sHrIm[0][kh][bv2][0];
    const _Float16* pZ = (quad < 2) ? &sHrIm[0][kh][bv2][0] : &sHrRe[0][kh][bv2][0];
    const float simsgn = (quad < 2) ? -1.0f : 1.0f;

    // ---- per-lane constants ----
    const float px = xc[v >> 11];
    const float py = yc[(v >> 5) & 63];
    const float pz = zc[v & 31];
    const float kstart = k0 + (kh ? 8.0f * dk : 0.0f);

    f32x4 accRe0 = {0,0,0,0}, accRe1 = {0,0,0,0};
    f32x4 accIm0 = {0,0,0,0}, accIm1 = {0,0,0,0};

    const char* bbase = (const char*)wsB + quad * 512 + nlo * 16;

    // ---- prefetch buffers: indexed only by unroll-constant r&1 ----
    half8 pb[2][4];
    half8 Xb[2], Zb[2];
    if (USE_WS) {
        pb[0][0] = *(const half8*)(bbase);
        pb[0][1] = *(const half8*)(bbase + 256);
        pb[0][2] = *(const half8*)(bbase + 2048);
        pb[0][3] = *(const half8*)(bbase + 2304);
    }
    Xb[0] = *(const half8*)(pX);
    Zb[0] = *(const half8*)(pZ);

    for (int t = 0; t < T; ++t) {
        // ---- Ht for this (voxel, t), fp32, sign folded into him ----
        const float txx = txp[t * 3 + 0], txy = txp[t * 3 + 1], txz = txp[t * 3 + 2];
        const float dxt = px - txx, dyt = py - txy, dzt = pz - txz;
        const float Rt = sqrtf(dxt * dxt + dyt * dyt + dzt * dzt);
        const float c = CT_SCALE * dzt * __builtin_amdgcn_rcpf(Rt);
        const float cIm = simsgn * c;
        float sph, cph, swp, cwp;
        __sincosf(kstart * Rt, &sph, &cph);
        __sincosf(dk * Rt, &swp, &cwp);
        float ur = cph, ui = sph;
        float ck  = c * (kstart * Rt);
        float ckI = cIm * (kstart * Rt);
        const float dck  = c * (dk * Rt);
        const float dckI = cIm * (dk * Rt);
        float hre[8], him[8];
#pragma unroll
        for (int j = 0; j < 8; ++j) {
            hre[j] = fmaf(c,   ur, -(ck * ui));    //  c*(ur - kR*ui)
            him[j] = fmaf(cIm, ui,  (ckI * ur));   // ±c*(ui + kR*ur)
            if (j < 7) {
                float nr = fmaf(ur, cwp, -(ui * swp));
                ui = fmaf(ur, swp, ui * cwp);
                ur = nr;
                ck  += dck;
                ckI += dckI;
            }
        }

        const char* bt = bbase + t * 32768;   // per-t base (no mutable chain)

#pragma unroll
        for (int r = 0; r < R; ++r) {
            const int cur = r & 1;             // compile-time after unroll
            const int nxt = cur ^ 1;

            if (USE_WS) {
                // prefetch next tr's B fragments (clamped on very last iter)
                const char* bn = (r == 7 && t == 7) ? bbase : (bt + (r + 1) * 4096);
                pb[nxt][0] = *(const half8*)(bn);
                pb[nxt][1] = *(const half8*)(bn + 256);
                pb[nxt][2] = *(const half8*)(bn + 2048);
                pb[nxt][3] = *(const half8*)(bn + 2304);
            } else {
                // fallback: direct gather into pb[cur] (no pipeline)
                const int tr = t * 8 + r;
                const int kb = kh * 8;
                const float* sA = (quad < 2) ? yr : yi;
                const float sgA = (quad < 2) ? 1.0f : -1.0f;
                const float* sB = (quad < 2) ? yi : yr;
#pragma unroll
                for (int j = 0; j < 8; ++j) {
                    int ba = kb * (T * R) + tr + j * (T * R);
                    pb[cur][0][j] = (_Float16)(sgA * sA[nlo * (K * T * R) + ba]);
                    pb[cur][1][j] = (_Float16)(sgA * sA[(16 + nlo) * (K * T * R) + ba]);
                    pb[cur][2][j] = (_Float16)(sB[nlo * (K * T * R) + ba]);
                    pb[cur][3][j] = (_Float16)(sB[(16 + nlo) * (K * T * R) + ba]);
                }
            }

            // prefetch next r's Hr fragments (address compile-time per unroll copy)
            Xb[nxt] = *(const half8*)(pX + ((r + 1) & 7) * 1024);
            Zb[nxt] = *(const half8*)(pZ + ((r + 1) & 7) * 1024);

            // A fragment: fp32 mixed-precision product, one fp16 rounding
            half8 X = Xb[cur], Z = Zb[cur];
            union { half8 v8; fp16x2 v2[4]; } A;
#pragma unroll
            for (int i = 0; i < 4; ++i) {
                float v0 = fmaf(hre[2 * i],     (float)X[2 * i],     him[2 * i]     * (float)Z[2 * i]);
                float v1 = fmaf(hre[2 * i + 1], (float)X[2 * i + 1], him[2 * i + 1] * (float)Z[2 * i + 1]);
                A.v2[i] = __builtin_amdgcn_cvt_pkrtz(v0, v1);
            }

            accRe0 = __builtin_amdgcn_mfma_f32_16x16x32_f16(A.v8, pb[cur][0], accRe0, 0, 0, 0);
            accRe1 = __builtin_amdgcn_mfma_f32_16x16x32_f16(A.v8, pb[cur][1], accRe1, 0, 0, 0);
            accIm0 = __builtin_amdgcn_mfma_f32_16x16x32_f16(A.v8, pb[cur][2], accIm0, 0, 0, 0);
            accIm1 = __builtin_amdgcn_mfma_f32_16x16x32_f16(A.v8, pb[cur][3], accIm1, 0, 0, 0);
        }
    }

    // ---- epilogue: magnitudes, store, block max ----
    // C/D layout: n = ntile*16 + (lane&15), m(voxel) = quad*4 + reg
    float mx = 0.0f;
#pragma unroll
    for (int reg = 0; reg < 4; ++reg) {
        const int vv = vb + quad * 4 + reg;
        float re0 = accRe0[reg], im0 = accIm0[reg];
        float m0 = sqrtf(re0 * re0 + im0 * im0);
        out[nlo * NVOX + vv] = m0;
        float re1 = accRe1[reg], im1 = accIm1[reg];
        float m1 = sqrtf(re1 * re1 + im1 * im1);
        out[(16 + nlo) * NVOX + vv] = m1;
        mx = fmaxf(mx, fmaxf(m0, m1));
    }
#pragma unroll
    for (int off = 32; off > 0; off >>= 1)
        mx = fmaxf(mx, __shfl_down(mx, off));
    if (lane == 0) s_wmax[wave] = mx;
    __syncthreads();
    if (threadIdx.x == 0) {
        float bm = fmaxf(fmaxf(s_wmax[0], s_wmax[1]), fmaxf(s_wmax[2], s_wmax[3]));
        atomicMax(maxslot, __float_as_uint(bm));
    }
}

// ---------------------------------------------------------------------------
// Normalize: out *= 1/max
// ---------------------------------------------------------------------------
__global__ void normalize_kernel(float* __restrict__ out,
                                 const unsigned int* __restrict__ maxslot, int n4) {
    int i = blockIdx.x * blockDim.x + threadIdx.x;
    float inv = 1.0f / __uint_as_float(*maxslot);
    if (i < n4) {
        float4* o = (float4*)out;
        float4 vv = o[i];
        vv.x *= inv; vv.y *= inv; vv.z *= inv; vv.w *= inv;
        o[i] = vv;
    }
}

extern "C" void kernel_launch(void* const* d_in, const int* in_sizes, int n_in,
                              void* d_out, int out_size, void* d_ws, size_t ws_size,
                              hipStream_t stream) {
    const float* freqs = (const float*)d_in[0];
    const float* txp   = (const float*)d_in[1];
    const float* rxp   = (const float*)d_in[2];
    const float* xc    = (const float*)d_in[3];
    const float* yc    = (const float*)d_in[4];
    const float* zc    = (const float*)d_in[5];
    const float* yr    = (const float*)d_in[6];
    const float* yi    = (const float*)d_in[7];
    float* out = (float*)d_out;

    unsigned int* maxslot = (unsigned int*)d_ws;
    _Float16* wsB = (_Float16*)((char*)d_ws + 256);
    const int use_ws = (ws_size >= WS_NEED) ? 1 : 0;

    prep_kernel<<<64, 256, 0, stream>>>(yr, yi, wsB, maxslot, use_ws);

    if (use_ws)
        kirch_mfma<true><<<NVOX / 64, 256, 0, stream>>>(
            freqs, txp, rxp, xc, yc, zc, wsB, yr, yi, out, maxslot);
    else
        kirch_mfma<false><<<NVOX / 64, 256, 0, stream>>>(
            freqs, txp, rxp, xc, yc, zc, wsB, yr, yi, out, maxslot);

    int n4 = out_size / 4;
    normalize_kernel<<<(n4 + 255) / 256, 256, 0, stream>>>(out, maxslot, n4);
}

// Round 9
// 242.275 us; speedup vs baseline: 1.3034x; 1.2535x over previous
//
#include <hip/hip_runtime.h>
#include <math.h>

namespace {
constexpr int K = 16, T = 8, R = 8, NB = 32;
constexpr int NX = 64, NY = 64, NZ = 32;
constexpr int NVOX = NX * NY * NZ;                 // 131072
constexpr float TWO_PI_OVER_C = (float)(6.283185307179586 / 299792458.0);
constexpr float CT_SCALE = 4.0f / 256.0f;          // scale split across Ht,Hr; cancels in normalize
constexpr float CR_SCALE = 1.0f / 256.0f;
// B table: [tr(64)][out(2)][quad(4)][n(32)][j(8)] halves = 262144 B
constexpr int B_HALVES = 64 * 2 * 4 * 32 * 8;      // 131072
constexpr size_t WS_NEED = 256 + (size_t)B_HALVES * 2;
}

typedef _Float16 half8 __attribute__((ext_vector_type(8)));
typedef __fp16 fp16x2 __attribute__((ext_vector_type(2)));   // cvt_pkrtz native type
typedef float f32x4 __attribute__((ext_vector_type(4)));

// ---------------------------------------------------------------------------
// Prep: zero max slot; build B fragments in ws.
// B[k'][n] per (tr, out):  k'<16 -> (out0: yre, out1: yim),  k'>=16 -> (out0: -yim, out1: yre)
// ---------------------------------------------------------------------------
__global__ void prep_kernel(const float* __restrict__ yr, const float* __restrict__ yi,
                            _Float16* __restrict__ wsB, unsigned int* __restrict__ maxslot,
                            int use_ws) {
    int id = blockIdx.x * 256 + threadIdx.x;   // 16384 threads
    if (id == 0) *maxslot = 0u;
    if (!use_ws || id >= 64 * 2 * 4 * 32) return;
    int n    = id & 31;
    int quad = (id >> 5) & 3;
    int outc = (id >> 7) & 1;
    int tr   = id >> 8;
    int t = tr >> 3, r = tr & 7;
    bool second = quad >= 2;                    // k' >= 16 half (pairs with AIm)
    const float* src = (outc == 0) ? (second ? yi : yr) : (second ? yr : yi);
    float sg = (outc == 0 && second) ? -1.0f : 1.0f;
    int base = n * (K * T * R) + ((quad & 1) * 8) * (T * R) + t * R + r;
    half8 h;
#pragma unroll
    for (int j = 0; j < 8; ++j)
        h[j] = (_Float16)(sg * src[base + j * (T * R)]);
    ((half8*)wsB)[id] = h;
}

// ---------------------------------------------------------------------------
// Main: per wave, 16-voxel x 32-batch complex tile via MFMA.
// A = 4*Ht*Hr. Hr in LDS (one cooperative build per block). DUAL-T: two
// independent Ht streams (t, t+1) per r-iteration share the Hr fragments;
// 8 MFMAs + 8 B loads per iter. NO state carried across loop back-edges in
// arrays (round 6-8 scratch lesson): all loads are named scalars with
// def-use inside one unrolled iteration; hre/him arrays die per t-iteration.
// A computed fp32 via v_fma_mix (accuracy), one fp16 rounding.
// ---------------------------------------------------------------------------
template <bool USE_WS>
__global__ __launch_bounds__(256, 2) void kirch_mfma(
    const float* __restrict__ freqs,
    const float* __restrict__ txp, const float* __restrict__ rxp,
    const float* __restrict__ xc, const float* __restrict__ yc, const float* __restrict__ zc,
    const _Float16* __restrict__ wsB,
    const float* __restrict__ yr, const float* __restrict__ yi,
    float* __restrict__ out, unsigned int* __restrict__ maxslot)
{
    __shared__ _Float16 sHrRe[8][2][64][8];   // [r][kh][vox][j]  16 KB
    __shared__ _Float16 sHrIm[8][2][64][8];   // 16 KB
    __shared__ float s_wmax[4];

    const int tid  = threadIdx.x;
    const int lane = tid & 63;
    const int wave = tid >> 6;
    const int nlo  = lane & 15;
    const int quad = lane >> 4;
    const int kh   = quad & 1;
    const int vb   = blockIdx.x * 64 + wave * 16;
    const int v    = vb + nlo;                 // this lane's voxel (fragment row m)
    const int bv2  = wave * 16 + nlo;          // block-local voxel index

    const float k0 = TWO_PI_OVER_C * freqs[0];
    const float dk = TWO_PI_OVER_C * (freqs[K - 1] - freqs[0]) * (1.0f / (K - 1));

    // ---- Phase 1: cooperatively build Hr table (64 vox x 8 r x 16 k) ----
#pragma unroll
    for (int s = 0; s < 2; ++s) {
        int task = tid + (s << 8);             // 512 tasks
        int bv = task & 63;
        int r  = task >> 6;
        int gv = blockIdx.x * 64 + bv;
        float qx = xc[gv >> 11];
        float qy = yc[(gv >> 5) & 63];
        float qz = zc[gv & 31];
        float rxx = rxp[r * 3 + 0], rxy = rxp[r * 3 + 1], rxz = rxp[r * 3 + 2];
        float dx = qx - rxx, dy = qy - rxy, dz = qz - rxz;
        float Rr = sqrtf(dx * dx + dy * dy + dz * dz);
        float c = CR_SCALE * dz * __builtin_amdgcn_rcpf(Rr);
        float sph, cph, swp, cwp;
        __sincosf(k0 * Rr, &sph, &cph);
        __sincosf(dk * Rr, &swp, &cwp);
        float ur = cph, ui = sph;
        float ck = c * (k0 * Rr);
        const float dck = c * (dk * Rr);
        float re[16], im[16];
#pragma unroll
        for (int kk = 0; kk < 16; ++kk) {
            re[kk] = fmaf(c, ur, -(ck * ui));   // c*(ur - kR*ui)
            im[kk] = fmaf(c, ui,  (ck * ur));   // c*(ui + kR*ur)
            float nr = fmaf(ur, cwp, -(ui * swp));
            ui = fmaf(ur, swp, ui * cwp);
            ur = nr;
            ck += dck;
        }
        union { half8 v8; fp16x2 v2[4]; } h;
#pragma unroll
        for (int kk2 = 0; kk2 < 2; ++kk2) {
#pragma unroll
            for (int i = 0; i < 4; ++i)
                h.v2[i] = __builtin_amdgcn_cvt_pkrtz(re[kk2 * 8 + 2 * i], re[kk2 * 8 + 2 * i + 1]);
            *(half8*)&sHrRe[r][kk2][bv][0] = h.v8;
#pragma unroll
            for (int i = 0; i < 4; ++i)
                h.v2[i] = __builtin_amdgcn_cvt_pkrtz(im[kk2 * 8 + 2 * i], im[kk2 * 8 + 2 * i + 1]);
            *(half8*)&sHrIm[r][kk2][bv][0] = h.v8;
        }
    }
    __syncthreads();

    // ---- X/Z plane base pointers (per lane class) ----
    // Re-quads: A = HtRe*HrRe - HtIm*HrIm  -> X=HrRe, Z=HrIm, him sign = -
    // Im-quads: A = HtRe*HrIm + HtIm*HrRe  -> X=HrIm, Z=HrRe, him sign = +
    const _Float16* pX = (quad < 2) ? &sHrRe[0][kh][bv2][0] : &sHrIm[0][kh][bv2][0];
    const _Float16* pZ = (quad < 2) ? &sHrIm[0][kh][bv2][0] : &sHrRe[0][kh][bv2][0];
    const float simsgn = (quad < 2) ? -1.0f : 1.0f;

    // ---- per-lane constants ----
    const float px = xc[v >> 11];
    const float py = yc[(v >> 5) & 63];
    const float pz = zc[v & 31];
    const float kstart = k0 + (kh ? 8.0f * dk : 0.0f);

    f32x4 accRe0 = {0,0,0,0}, accRe1 = {0,0,0,0};
    f32x4 accIm0 = {0,0,0,0}, accIm1 = {0,0,0,0};

    const char* bbase = (const char*)wsB + quad * 512 + nlo * 16;

    for (int t = 0; t < T; t += 2) {
        // ---- Ht stream 0 (t): fp32, sign folded into him0 ----
        float hre0[8], him0[8];
        {
            const float txx = txp[t * 3 + 0], txy = txp[t * 3 + 1], txz = txp[t * 3 + 2];
            const float dxt = px - txx, dyt = py - txy, dzt = pz - txz;
            const float Rt = sqrtf(dxt * dxt + dyt * dyt + dzt * dzt);
            const float c = CT_SCALE * dzt * __builtin_amdgcn_rcpf(Rt);
            const float cIm = simsgn * c;
            float sph, cph, swp, cwp;
            __sincosf(kstart * Rt, &sph, &cph);
            __sincosf(dk * Rt, &swp, &cwp);
            float ur = cph, ui = sph;
            float ck  = c * (kstart * Rt);
            float ckI = cIm * (kstart * Rt);
            const float dck  = c * (dk * Rt);
            const float dckI = cIm * (dk * Rt);
#pragma unroll
            for (int j = 0; j < 8; ++j) {
                hre0[j] = fmaf(c,   ur, -(ck * ui));
                him0[j] = fmaf(cIm, ui,  (ckI * ur));
                if (j < 7) {
                    float nr = fmaf(ur, cwp, -(ui * swp));
                    ui = fmaf(ur, swp, ui * cwp);
                    ur = nr;
                    ck  += dck;
                    ckI += dckI;
                }
            }
        }
        // ---- Ht stream 1 (t+1) ----
        float hre1[8], him1[8];
        {
            const float txx = txp[(t + 1) * 3 + 0], txy = txp[(t + 1) * 3 + 1], txz = txp[(t + 1) * 3 + 2];
            const float dxt = px - txx, dyt = py - txy, dzt = pz - txz;
            const float Rt = sqrtf(dxt * dxt + dyt * dyt + dzt * dzt);
            const float c = CT_SCALE * dzt * __builtin_amdgcn_rcpf(Rt);
            const float cIm = simsgn * c;
            float sph, cph, swp, cwp;
            __sincosf(kstart * Rt, &sph, &cph);
            __sincosf(dk * Rt, &swp, &cwp);
            float ur = cph, ui = sph;
            float ck  = c * (kstart * Rt);
            float ckI = cIm * (kstart * Rt);
            const float dck  = c * (dk * Rt);
            const float dckI = cIm * (dk * Rt);
#pragma unroll
            for (int j = 0; j < 8; ++j) {
                hre1[j] = fmaf(c,   ur, -(ck * ui));
                him1[j] = fmaf(cIm, ui,  (ckI * ur));
                if (j < 7) {
                    float nr = fmaf(ur, cwp, -(ui * swp));
                    ui = fmaf(ur, swp, ui * cwp);
                    ur = nr;
                    ck  += dck;
                    ckI += dckI;
                }
            }
        }

        const char* bt0 = bbase + (size_t)(t * 8) * 4096;
        const char* bt1 = bbase + (size_t)((t + 1) * 8) * 4096;

#pragma unroll
        for (int r = 0; r < R; ++r) {
            // Hr fragments (shared by both t-streams)
            half8 X = *(const half8*)(pX + r * 1024);
            half8 Z = *(const half8*)(pZ + r * 1024);

            // B fragments for both streams — named scalars, def-use in-iteration
            half8 b000, b001, b010, b011, b100, b101, b110, b111;
            if (USE_WS) {
                const char* bp0 = bt0 + r * 4096;
                const char* bp1 = bt1 + r * 4096;
                b000 = *(const half8*)(bp0);             // t,   Re-out, ntile 0
                b001 = *(const half8*)(bp0 + 256);       // t,   Re-out, ntile 1
                b010 = *(const half8*)(bp0 + 2048);      // t,   Im-out, ntile 0
                b011 = *(const half8*)(bp0 + 2304);      // t,   Im-out, ntile 1
                b100 = *(const half8*)(bp1);             // t+1, Re-out, ntile 0
                b101 = *(const half8*)(bp1 + 256);
                b110 = *(const half8*)(bp1 + 2048);
                b111 = *(const half8*)(bp1 + 2304);
            } else {
                const int kb = kh * 8;
                const float* sA = (quad < 2) ? yr : yi;
                const float sgA = (quad < 2) ? 1.0f : -1.0f;
                const float* sB = (quad < 2) ? yi : yr;
#pragma unroll
                for (int j = 0; j < 8; ++j) {
                    int ba0 = kb * (T * R) + (t * 8 + r) + j * (T * R);
                    int ba1 = kb * (T * R) + ((t + 1) * 8 + r) + j * (T * R);
                    b000[j] = (_Float16)(sgA * sA[nlo * (K * T * R) + ba0]);
                    b001[j] = (_Float16)(sgA * sA[(16 + nlo) * (K * T * R) + ba0]);
                    b010[j] = (_Float16)(sB[nlo * (K * T * R) + ba0]);
                    b011[j] = (_Float16)(sB[(16 + nlo) * (K * T * R) + ba0]);
                    b100[j] = (_Float16)(sgA * sA[nlo * (K * T * R) + ba1]);
                    b101[j] = (_Float16)(sgA * sA[(16 + nlo) * (K * T * R) + ba1]);
                    b110[j] = (_Float16)(sB[nlo * (K * T * R) + ba1]);
                    b111[j] = (_Float16)(sB[(16 + nlo) * (K * T * R) + ba1]);
                }
            }

            // A fragments: fp32 mixed-precision products, one fp16 rounding each
            union { half8 v8; fp16x2 v2[4]; } A0, A1;
#pragma unroll
            for (int i = 0; i < 4; ++i) {
                float v0 = fmaf(hre0[2 * i],     (float)X[2 * i],     him0[2 * i]     * (float)Z[2 * i]);
                float v1 = fmaf(hre0[2 * i + 1], (float)X[2 * i + 1], him0[2 * i + 1] * (float)Z[2 * i + 1]);
                A0.v2[i] = __builtin_amdgcn_cvt_pkrtz(v0, v1);
                float w0 = fmaf(hre1[2 * i],     (float)X[2 * i],     him1[2 * i]     * (float)Z[2 * i]);
                float w1 = fmaf(hre1[2 * i + 1], (float)X[2 * i + 1], him1[2 * i + 1] * (float)Z[2 * i + 1]);
                A1.v2[i] = __builtin_amdgcn_cvt_pkrtz(w0, w1);
            }

            accRe0 = __builtin_amdgcn_mfma_f32_16x16x32_f16(A0.v8, b000, accRe0, 0, 0, 0);
            accRe1 = __builtin_amdgcn_mfma_f32_16x16x32_f16(A0.v8, b001, accRe1, 0, 0, 0);
            accIm0 = __builtin_amdgcn_mfma_f32_16x16x32_f16(A0.v8, b010, accIm0, 0, 0, 0);
            accIm1 = __builtin_amdgcn_mfma_f32_16x16x32_f16(A0.v8, b011, accIm1, 0, 0, 0);
            accRe0 = __builtin_amdgcn_mfma_f32_16x16x32_f16(A1.v8, b100, accRe0, 0, 0, 0);
            accRe1 = __builtin_amdgcn_mfma_f32_16x16x32_f16(A1.v8, b101, accRe1, 0, 0, 0);
            accIm0 = __builtin_amdgcn_mfma_f32_16x16x32_f16(A1.v8, b110, accIm0, 0, 0, 0);
            accIm1 = __builtin_amdgcn_mfma_f32_16x16x32_f16(A1.v8, b111, accIm1, 0, 0, 0);
        }
    }

    // ---- epilogue: magnitudes, store, block max ----
    // C/D layout: n = ntile*16 + (lane&15), m(voxel) = quad*4 + reg
    float mx = 0.0f;
#pragma unroll
    for (int reg = 0; reg < 4; ++reg) {
        const int vv = vb + quad * 4 + reg;
        float re0 = accRe0[reg], im0 = accIm0[reg];
        float m0 = sqrtf(re0 * re0 + im0 * im0);
        out[nlo * NVOX + vv] = m0;
        float re1 = accRe1[reg], im1 = accIm1[reg];
        float m1 = sqrtf(re1 * re1 + im1 * im1);
        out[(16 + nlo) * NVOX + vv] = m1;
        mx = fmaxf(mx, fmaxf(m0, m1));
    }
#pragma unroll
    for (int off = 32; off > 0; off >>= 1)
        mx = fmaxf(mx, __shfl_down(mx, off));
    if (lane == 0) s_wmax[wave] = mx;
    __syncthreads();
    if (threadIdx.x == 0) {
        float bm = fmaxf(fmaxf(s_wmax[0], s_wmax[1]), fmaxf(s_wmax[2], s_wmax[3]));
        atomicMax(maxslot, __float_as_uint(bm));
    }
}

// ---------------------------------------------------------------------------
// Normalize: out *= 1/max
// ---------------------------------------------------------------------------
__global__ void normalize_kernel(float* __restrict__ out,
                                 const unsigned int* __restrict__ maxslot, int n4) {
    int i = blockIdx.x * blockDim.x + threadIdx.x;
    float inv = 1.0f / __uint_as_float(*maxslot);
    if (i < n4) {
        float4* o = (float4*)out;
        float4 vv = o[i];
        vv.x *= inv; vv.y *= inv; vv.z *= inv; vv.w *= inv;
        o[i] = vv;
    }
}

extern "C" void kernel_launch(void* const* d_in, const int* in_sizes, int n_in,
                              void* d_out, int out_size, void* d_ws, size_t ws_size,
                              hipStream_t stream) {
    const float* freqs = (const float*)d_in[0];
    const float* txp   = (const float*)d_in[1];
    const float* rxp   = (const float*)d_in[2];
    const float* xc    = (const float*)d_in[3];
    const float* yc    = (const float*)d_in[4];
    const float* zc    = (const float*)d_in[5];
    const float* yr    = (const float*)d_in[6];
    const float* yi    = (const float*)d_in[7];
    float* out = (float*)d_out;

    unsigned int* maxslot = (unsigned int*)d_ws;
    _Float16* wsB = (_Float16*)((char*)d_ws + 256);
    const int use_ws = (ws_size >= WS_NEED) ? 1 : 0;

    prep_kernel<<<64, 256, 0, stream>>>(yr, yi, wsB, maxslot, use_ws);

    if (use_ws)
        kirch_mfma<true><<<NVOX / 64, 256, 0, stream>>>(
            freqs, txp, rxp, xc, yc, zc, wsB, yr, yi, out, maxslot);
    else
        kirch_mfma<false><<<NVOX / 64, 256, 0, stream>>>(
            freqs, txp, rxp, xc, yc, zc, wsB, yr, yi, out, maxslot);

    int n4 = out_size / 4;
    normalize_kernel<<<(n4 + 255) / 256, 256, 0, stream>>>(out, maxslot, n4);
}